// Round 1
// baseline (780.005 us; speedup 1.0000x reference)
//
#include <hip/hip_runtime.h>

#define C    512
#define NDIM 1024
#define BDIM 8
#define TDIM 4
#define HDIM 8
#define CN   (C*NDIM)        // 524288
#define BCN  (BDIM*CN)       // 4194304

// ---------------------------------------------------------------------------
// fp32 GEMM: Y[b,o,n] = sum_c W[rowOff+o,c] * X[b,c,n] + bias[rowOff+o]
// tile 64x64, BK=16, 256 threads, 4x4 micro-tile per thread.
// ---------------------------------------------------------------------------
__global__ __launch_bounds__(256) void gemm_in_k(
    const float* __restrict__ W, const float* __restrict__ bias,
    const float* __restrict__ X, float* __restrict__ Y, int rowOff)
{
    __shared__ float As[16][68];   // As[k][m], pad 68 keeps 16B align + spreads banks
    __shared__ float Bs[16][68];   // Bs[k][n]
    const int tid = threadIdx.x;
    const int b  = blockIdx.z;
    const int m0 = blockIdx.y * 64;
    const int n0 = blockIdx.x * 64;
    const float* Xb = X + (size_t)b * CN;

    const int am = tid >> 2;        // 0..63   A row (m)
    const int ak = (tid & 3) * 4;   // 0,4,8,12 A col (k)
    const int bk = tid >> 4;        // 0..15   B row (k)
    const int bn = (tid & 15) * 4;  // 0..60   B col (n)
    const int tx = tid & 15, ty = tid >> 4;

    float acc[4][4];
    #pragma unroll
    for (int i = 0; i < 4; i++)
        #pragma unroll
        for (int j = 0; j < 4; j++) acc[i][j] = 0.f;

    for (int k0 = 0; k0 < C; k0 += 16) {
        float4 a  = *(const float4*)&W [(size_t)(rowOff + m0 + am) * C + k0 + ak];
        float4 bb = *(const float4*)&Xb[(size_t)(k0 + bk) * NDIM + n0 + bn];
        __syncthreads();
        As[ak + 0][am] = a.x; As[ak + 1][am] = a.y;
        As[ak + 2][am] = a.z; As[ak + 3][am] = a.w;
        *(float4*)&Bs[bk][bn] = bb;
        __syncthreads();
        #pragma unroll
        for (int k = 0; k < 16; k++) {
            float av[4], bv[4];
            *(float4*)av = *(const float4*)&As[k][ty * 4];
            *(float4*)bv = *(const float4*)&Bs[k][tx * 4];
            #pragma unroll
            for (int i = 0; i < 4; i++)
                #pragma unroll
                for (int j = 0; j < 4; j++)
                    acc[i][j] += av[i] * bv[j];
        }
    }
    #pragma unroll
    for (int i = 0; i < 4; i++) {
        float bsv = bias[rowOff + m0 + ty * 4 + i];
        float4 o4 = make_float4(acc[i][0] + bsv, acc[i][1] + bsv,
                                acc[i][2] + bsv, acc[i][3] + bsv);
        *(float4*)&Y[(size_t)b * CN + (size_t)(m0 + ty * 4 + i) * NDIM + n0 + tx * 4] = o4;
    }
}

// ---------------------------------------------------------------------------
// fp32 GEMM over binary spikes: Z[t,b,o,n] = sum_c W[o,c]*S_t[b,c,n] + bias[o]
// S stored as byte per (b,c,n), bit t = spike at timestep t.
// ---------------------------------------------------------------------------
__global__ __launch_bounds__(256) void gemm_proj_k(
    const float* __restrict__ W, const float* __restrict__ bias,
    const unsigned char* __restrict__ S, float* __restrict__ Z)
{
    __shared__ float As[16][68];
    __shared__ float Bs[16][68];
    const int tid = threadIdx.x;
    const int zb = blockIdx.z;            // t*8+b
    const int t = zb >> 3, b = zb & 7;
    const int m0 = blockIdx.y * 64;
    const int n0 = blockIdx.x * 64;
    const unsigned char* Sb = S + (size_t)b * CN;

    const int am = tid >> 2;
    const int ak = (tid & 3) * 4;
    const int bk = tid >> 4;
    const int bn = (tid & 15) * 4;
    const int tx = tid & 15, ty = tid >> 4;

    float acc[4][4];
    #pragma unroll
    for (int i = 0; i < 4; i++)
        #pragma unroll
        for (int j = 0; j < 4; j++) acc[i][j] = 0.f;

    for (int k0 = 0; k0 < C; k0 += 16) {
        float4 a = *(const float4*)&W[(size_t)(m0 + am) * C + k0 + ak];
        uchar4 s4 = *(const uchar4*)&Sb[(size_t)(k0 + bk) * NDIM + n0 + bn];
        __syncthreads();
        As[ak + 0][am] = a.x; As[ak + 1][am] = a.y;
        As[ak + 2][am] = a.z; As[ak + 3][am] = a.w;
        Bs[bk][bn + 0] = (float)((s4.x >> t) & 1);
        Bs[bk][bn + 1] = (float)((s4.y >> t) & 1);
        Bs[bk][bn + 2] = (float)((s4.z >> t) & 1);
        Bs[bk][bn + 3] = (float)((s4.w >> t) & 1);
        __syncthreads();
        #pragma unroll
        for (int k = 0; k < 16; k++) {
            float av[4], bv[4];
            *(float4*)av = *(const float4*)&As[k][ty * 4];
            *(float4*)bv = *(const float4*)&Bs[k][tx * 4];
            #pragma unroll
            for (int i = 0; i < 4; i++)
                #pragma unroll
                for (int j = 0; j < 4; j++)
                    acc[i][j] += av[i] * bv[j];
        }
    }
    #pragma unroll
    for (int i = 0; i < 4; i++) {
        float bsv = bias[m0 + ty * 4 + i];
        float4 o4 = make_float4(acc[i][0] + bsv, acc[i][1] + bsv,
                                acc[i][2] + bsv, acc[i][3] + bsv);
        *(float4*)&Z[(size_t)zb * CN + (size_t)(m0 + ty * 4 + i) * NDIM + n0 + tx * 4] = o4;
    }
}

// ---------------------------------------------------------------------------
// per-channel mean over (outer, N); X layout [outer][C][N]
// ---------------------------------------------------------------------------
__global__ __launch_bounds__(256) void chan_sum_k(
    const float* __restrict__ X, float* __restrict__ mean, int outer)
{
    __shared__ float red[256];
    const int o = blockIdx.x, tid = threadIdx.x;
    const int total = outer * NDIM;
    float s = 0.f;
    for (int i = tid; i < total; i += 256) {
        int ou = i >> 10, n = i & 1023;
        s += X[(size_t)(ou * C + o) * NDIM + n];
    }
    red[tid] = s; __syncthreads();
    for (int off = 128; off > 0; off >>= 1) {
        if (tid < off) red[tid] += red[tid + off];
        __syncthreads();
    }
    if (tid == 0) mean[o] = red[0] / (float)total;
}

// second pass: var = mean((x-m)^2), store rstd = 1/sqrt(var+eps)
__global__ __launch_bounds__(256) void chan_var_k(
    const float* __restrict__ X, const float* __restrict__ mean,
    float* __restrict__ rstd, int outer)
{
    __shared__ float red[256];
    const int o = blockIdx.x, tid = threadIdx.x;
    const int total = outer * NDIM;
    const float m = mean[o];
    float s = 0.f;
    for (int i = tid; i < total; i += 256) {
        int ou = i >> 10, n = i & 1023;
        float d = X[(size_t)(ou * C + o) * NDIM + n] - m;
        s += d * d;
    }
    red[tid] = s; __syncthreads();
    for (int off = 128; off > 0; off >>= 1) {
        if (tid < off) red[tid] += red[tid + off];
        __syncthreads();
    }
    if (tid == 0) rstd[o] = 1.f / sqrtf(red[0] / (float)total + 1e-5f);
}

// ---------------------------------------------------------------------------
// BN + 4-step LIF (vth=1) on time-constant input -> 4 spike bits per element
// ---------------------------------------------------------------------------
__global__ __launch_bounds__(256) void bn_lif_pack_k(
    const float* __restrict__ Y, const float* __restrict__ mean,
    const float* __restrict__ rstd, const float* __restrict__ gamma,
    const float* __restrict__ beta, unsigned char* __restrict__ spk)
{
    const int idx = blockIdx.x * 256 + threadIdx.x;   // (b,o,n) flat over BCN
    const int o = (idx >> 10) & (C - 1);
    float y = Y[idx];
    float x = gamma[o] * (y - mean[o]);
    x = x * rstd[o] + beta[o];
    float v = 0.f; unsigned bits = 0;
    #pragma unroll
    for (int t = 0; t < 4; t++) {
        v += (x - v) * 0.5f;
        if (v - 1.0f >= 0.f) { bits |= (1u << t); v = 0.f; }
    }
    spk[idx] = (unsigned char)bits;
}

// ---------------------------------------------------------------------------
// Q pack: qm[t][b][h][n] u64, bit dd = spike of channel h*64+dd (LDS transpose)
// grid (b*h, n/64)
// ---------------------------------------------------------------------------
__global__ __launch_bounds__(256) void qpack_k(
    const unsigned char* __restrict__ spk, unsigned long long* __restrict__ qm)
{
    __shared__ unsigned char tile[64][80];   // 80 = 16B-aligned rows, bank spread
    const int tid = threadIdx.x;
    const int bh = blockIdx.x; const int h = bh & 7, b = bh >> 3;
    const int n0 = blockIdx.y * 64;
    {
        int dd = tid >> 2, seg = tid & 3;
        *(uint4*)&tile[dd][seg * 16] =
            *(const uint4*)&spk[(size_t)(b * C + h * 64 + dd) * NDIM + n0 + seg * 16];
    }
    __syncthreads();
    const int lane = tid & 63, wv = tid >> 6;
    for (int i = 0; i < 16; i++) {
        int j = wv * 16 + i;
        unsigned s = tile[lane][j];
        #pragma unroll
        for (int t = 0; t < 4; t++) {
            unsigned long long m = __ballot((s >> t) & 1);
            if (lane == t)
                qm[(size_t)((t * BDIM + b) * HDIM + h) * NDIM + n0 + j] = m;
        }
    }
}

// ---------------------------------------------------------------------------
// K/V pack over n: bits[t][b][c][w] u64, bit j = spike at n = w*64+j
// wave per (b,c,w); 4 waves per block
// ---------------------------------------------------------------------------
__global__ __launch_bounds__(256) void kv_pack_k(
    const unsigned char* __restrict__ spk, unsigned long long* __restrict__ bits)
{
    const int tid = threadIdx.x;
    const int gw = blockIdx.x * 4 + (tid >> 6);       // (b*512+c)*16+w
    const int lane = tid & 63;
    const int w = gw & 15, c = (gw >> 4) & (C - 1), b = gw >> 13;
    unsigned s = spk[(size_t)(b * C + c) * NDIM + w * 64 + lane];
    #pragma unroll
    for (int t = 0; t < 4; t++) {
        unsigned long long m = __ballot((s >> t) & 1);
        if (lane == t)
            bits[(size_t)((t * BDIM + b) * C + c) * 16 + w] = m;
    }
}

// ---------------------------------------------------------------------------
// ktv[t,b,h,dd,e] = sum_n K[n,dd]*V[n,e]  = popcount over bitpacked n
// grid 256 = (t,b,h); exact integer counts (<=1024) stored u16
// ---------------------------------------------------------------------------
__global__ __launch_bounds__(256) void ktv_k(
    const unsigned long long* __restrict__ kb,
    const unsigned long long* __restrict__ vb, unsigned short* __restrict__ ktv)
{
    __shared__ unsigned long long ks[64][17];
    __shared__ unsigned long long vs[64][17];
    const int tid = threadIdx.x;
    const int g = blockIdx.x;                 // (t*8+b)*8+h
    const int h = g & 7, b = (g >> 3) & 7, t = g >> 6;
    const size_t base = ((size_t)(t * BDIM + b) * C + h * 64) * 16;
    {
        int r = tid >> 2, w0 = (tid & 3) * 4;
        #pragma unroll
        for (int j = 0; j < 4; j++) {
            ks[r][w0 + j] = kb[base + r * 16 + w0 + j];
            vs[r][w0 + j] = vb[base + r * 16 + w0 + j];
        }
    }
    __syncthreads();
    const int dd = tid >> 2, e0 = (tid & 3) * 16;
    unsigned long long kr[16];
    #pragma unroll
    for (int w = 0; w < 16; w++) kr[w] = ks[dd][w];
    #pragma unroll
    for (int i = 0; i < 16; i++) {
        int e = e0 + i;
        int s = 0;
        #pragma unroll
        for (int w = 0; w < 16; w++) s += __popcll(kr[w] & vs[e][w]);
        ktv[(size_t)(g * 64 + dd) * 64 + e] = (unsigned short)s;
    }
}

// ---------------------------------------------------------------------------
// att[t,b,h,n,e] = 0.125 * sum_dd Q[n,dd]*ktv[dd,e]  (exact int accumulate,
// wave-uniform q-mask -> ffs loop), fused with attn LIF (vth=0.5) over t.
// Output: packed spike byte spk2[b][h*64+e][n].
// grid (b*h, n/64); wave = 64 e-lanes.
// ---------------------------------------------------------------------------
__global__ __launch_bounds__(256) void att_lif_k(
    const unsigned short* __restrict__ ktv,
    const unsigned long long* __restrict__ qm, unsigned char* __restrict__ spk2)
{
    __shared__ unsigned short ks[4][64][64];   // 32 KB
    const int tid = threadIdx.x;
    const int bh = blockIdx.x; const int h = bh & 7, b = bh >> 3;
    const int n0 = blockIdx.y * 64;
    #pragma unroll
    for (int t = 0; t < 4; t++) {
        const unsigned int* src =
            (const unsigned int*)&ktv[(size_t)((t * BDIM + b) * HDIM + h) * 4096];
        unsigned int* dst = (unsigned int*)&ks[t][0][0];
        #pragma unroll
        for (int j = 0; j < 8; j++) dst[tid + 256 * j] = src[tid + 256 * j];
    }
    __syncthreads();
    const int lane = tid & 63, wv = tid >> 6;
    union { unsigned char c[16]; uint4 v4; } ob;
    #pragma unroll
    for (int i = 0; i < 16; i++) {
        const int n = n0 + wv * 16 + i;
        float v = 0.f; unsigned bits = 0;
        #pragma unroll
        for (int t = 0; t < 4; t++) {
            unsigned long long m = qm[(size_t)((t * BDIM + b) * HDIM + h) * NDIM + n];
            int acc = 0;
            while (m) {                       // wave-uniform loop
                int dd = __ffsll(m) - 1;
                m &= m - 1;
                acc += ks[t][dd][lane];
            }
            float x = (float)acc * 0.125f;    // exact: acc integer < 2^17
            v += (x - v) * 0.5f;
            if (v - 0.5f >= 0.f) { bits |= (1u << t); v = 0.f; }
        }
        ob.c[i] = (unsigned char)bits;
    }
    *(uint4*)&spk2[(size_t)(b * C + h * 64 + lane) * NDIM + n0 + wv * 16] = ob.v4;
}

// ---------------------------------------------------------------------------
// Final: BN + LIF (vth=1, time-varying input) in place over d_out.
// thread per (b,o,n), loops t (reads 4 z, writes 4 spikes, same addresses)
// ---------------------------------------------------------------------------
__global__ __launch_bounds__(256) void final_bn_lif_k(
    float* __restrict__ Z, const float* __restrict__ mean,
    const float* __restrict__ rstd, const float* __restrict__ gamma,
    const float* __restrict__ beta)
{
    const int idx = blockIdx.x * 256 + threadIdx.x;   // over BCN
    const int o = (idx >> 10) & (C - 1);
    const float m = mean[o], rs = rstd[o], g = gamma[o], bt = beta[o];
    float v = 0.f;
    float outs[4];
    #pragma unroll
    for (int t = 0; t < 4; t++) {
        float z = Z[(size_t)t * BCN + idx];
        float x = g * (z - m);
        x = x * rs + bt;
        v += (x - v) * 0.5f;
        float s = (v - 1.0f >= 0.f) ? 1.f : 0.f;
        v *= (1.f - s);
        outs[t] = s;
    }
    #pragma unroll
    for (int t = 0; t < 4; t++) Z[(size_t)t * BCN + idx] = outs[t];
}

// ---------------------------------------------------------------------------
extern "C" void kernel_launch(void* const* d_in, const int* in_sizes, int n_in,
                              void* d_out, int out_size, void* d_ws, size_t ws_size,
                              hipStream_t stream)
{
    const float* q     = (const float*)d_in[0];
    const float* k     = (const float*)d_in[1];
    const float* v     = (const float*)d_in[2];
    const float* W     = (const float*)d_in[3];
    const float* Wb    = (const float*)d_in[4];
    const float* qg    = (const float*)d_in[5];
    const float* qb    = (const float*)d_in[6];
    const float* kg    = (const float*)d_in[7];
    const float* kbt   = (const float*)d_in[8];
    const float* vg    = (const float*)d_in[9];
    const float* vbt   = (const float*)d_in[10];
    const float* pw    = (const float*)d_in[11];
    const float* pb    = (const float*)d_in[12];
    const float* pg    = (const float*)d_in[13];
    const float* pbeta = (const float*)d_in[14];

    // workspace carve (~29 MB)
    char* p = (char*)d_ws;
    float* Y = (float*)p;                                   p += (size_t)BCN * 4;
    unsigned char* spk = (unsigned char*)p;                 p += (size_t)BCN;
    unsigned long long* qmv = (unsigned long long*)p;       p += (size_t)TDIM * BDIM * HDIM * NDIM * 8;
    unsigned long long* kbits = (unsigned long long*)p;     p += (size_t)TDIM * BDIM * C * 16 * 8;
    unsigned long long* vbits = (unsigned long long*)p;     p += (size_t)TDIM * BDIM * C * 16 * 8;
    unsigned short* ktv = (unsigned short*)p;               p += (size_t)TDIM * BDIM * HDIM * 64 * 64 * 2;
    float* mean = (float*)p;                                p += 4096;
    float* rstd = (float*)p;                                p += 4096;

    const float* Xs[3] = {q, k, v};
    const float* Gs[3] = {qg, kg, vg};
    const float* Bt[3] = {qb, kbt, vbt};

    for (int br = 0; br < 3; ++br) {
        gemm_in_k<<<dim3(16, 8, 8), 256, 0, stream>>>(W, Wb, Xs[br], Y, br * C);
        chan_sum_k<<<C, 256, 0, stream>>>(Y, mean, BDIM);
        chan_var_k<<<C, 256, 0, stream>>>(Y, mean, rstd, BDIM);
        bn_lif_pack_k<<<BCN / 256, 256, 0, stream>>>(Y, mean, rstd, Gs[br], Bt[br], spk);
        if (br == 0)
            qpack_k<<<dim3(64, 16), 256, 0, stream>>>(spk, qmv);
        else
            kv_pack_k<<<16384, 256, 0, stream>>>(spk, br == 1 ? kbits : vbits);
    }
    ktv_k<<<256, 256, 0, stream>>>(kbits, vbits, ktv);
    att_lif_k<<<dim3(64, 16), 256, 0, stream>>>(ktv, qmv, spk);   // spk reused as spk2
    gemm_proj_k<<<dim3(16, 8, 32), 256, 0, stream>>>(pw, pb, spk, (float*)d_out);
    chan_sum_k<<<C, 256, 0, stream>>>((float*)d_out, mean, TDIM * BDIM);
    chan_var_k<<<C, 256, 0, stream>>>((float*)d_out, mean, rstd, TDIM * BDIM);
    final_bn_lif_k<<<BCN / 256, 256, 0, stream>>>((float*)d_out, mean, rstd, pg, pbeta);
}

// Round 3
// 645.281 us; speedup vs baseline: 1.2088x; 1.2088x over previous
//
#include <hip/hip_runtime.h>

#define C    512
#define NDIM 1024
#define BDIM 8
#define TDIM 4
#define HDIM 8
#define CN   (C*NDIM)        // 524288
#define BCN  (BDIM*CN)       // 4194304

typedef unsigned short u16;
typedef unsigned int   u32;
typedef unsigned long long u64;
typedef __attribute__((ext_vector_type(8))) short bf8v;   // 8 bf16 (4 VGPR)
typedef __attribute__((ext_vector_type(4))) float f4v;    // 4 fp32 acc

// round-to-nearest-even f32 -> bf16 (finite inputs only)
__device__ __forceinline__ u16 f2bf(float f) {
    u32 u = __float_as_uint(f);
    u32 r = u + 0x7FFFu + ((u >> 16) & 1u);
    return (u16)(r >> 16);
}
__device__ __forceinline__ float bf2f(u16 h) { return __uint_as_float((u32)h << 16); }

#if defined(__has_builtin)
#if __has_builtin(__builtin_amdgcn_global_load_lds)
#define HAS_GLL 1
#endif
#endif
#ifdef HAS_GLL
#define GLD(gp, lp) __builtin_amdgcn_global_load_lds( \
    (const __attribute__((address_space(1))) u32*)(gp), \
    (__attribute__((address_space(3))) u32*)(lp), 16, 0, 0)
#else
#define GLD(gp, lp) (*(uint4*)(lp) = *(const uint4*)(const void*)(gp))
#endif

// ---------------------------------------------------------------------------
// R1-proven fp32 GEMM: Y[b,o,n] = sum_c W[rowOff+o,c]*X[b,c,n] + bias
// ---------------------------------------------------------------------------
__global__ __launch_bounds__(256) void gemm_in_k(
    const float* __restrict__ W, const float* __restrict__ bias,
    const float* __restrict__ X, float* __restrict__ Y, int rowOff)
{
    __shared__ float As[16][68];
    __shared__ float Bs[16][68];
    const int tid = threadIdx.x;
    const int b  = blockIdx.z;
    const int m0 = blockIdx.y * 64;
    const int n0 = blockIdx.x * 64;
    const float* Xb = X + (size_t)b * CN;

    const int am = tid >> 2;
    const int ak = (tid & 3) * 4;
    const int bk = tid >> 4;
    const int bn = (tid & 15) * 4;
    const int tx = tid & 15, ty = tid >> 4;

    float acc[4][4];
    #pragma unroll
    for (int i = 0; i < 4; i++)
        #pragma unroll
        for (int j = 0; j < 4; j++) acc[i][j] = 0.f;

    for (int k0 = 0; k0 < C; k0 += 16) {
        float4 a  = *(const float4*)&W [(size_t)(rowOff + m0 + am) * C + k0 + ak];
        float4 bb = *(const float4*)&Xb[(size_t)(k0 + bk) * NDIM + n0 + bn];
        __syncthreads();
        As[ak + 0][am] = a.x; As[ak + 1][am] = a.y;
        As[ak + 2][am] = a.z; As[ak + 3][am] = a.w;
        *(float4*)&Bs[bk][bn] = bb;
        __syncthreads();
        #pragma unroll
        for (int k = 0; k < 16; k++) {
            float av[4], bv[4];
            *(float4*)av = *(const float4*)&As[k][ty * 4];
            *(float4*)bv = *(const float4*)&Bs[k][tx * 4];
            #pragma unroll
            for (int i = 0; i < 4; i++)
                #pragma unroll
                for (int j = 0; j < 4; j++)
                    acc[i][j] += av[i] * bv[j];
        }
    }
    #pragma unroll
    for (int i = 0; i < 4; i++) {
        float bsv = bias[rowOff + m0 + ty * 4 + i];
        float4 o4 = make_float4(acc[i][0] + bsv, acc[i][1] + bsv,
                                acc[i][2] + bsv, acc[i][3] + bsv);
        *(float4*)&Y[(size_t)b * CN + (size_t)(m0 + ty * 4 + i) * NDIM + n0 + tx * 4] = o4;
    }
}

// ---------------------------------------------------------------------------
// Split PW (512x512) into exact 3-way bf16 planes (runs after att_lif;
// Ps aliases the then-dead qmv buffer).
// ---------------------------------------------------------------------------
__global__ __launch_bounds__(256) void split_pw_k(
    const float* __restrict__ PW, u16* __restrict__ Ps)
{
    const int idx = blockIdx.x * 256 + threadIdx.x;   // 512*512 = 262144
    float x = PW[idx];
    u16 h1 = f2bf(x); float r1 = x - bf2f(h1);
    u16 h2 = f2bf(r1); float r2 = r1 - bf2f(h2);
    u16 h3 = f2bf(r2);
    Ps[idx] = h1; Ps[idx + 262144] = h2; Ps[idx + 2 * 262144] = h3;
}

// ---------------------------------------------------------------------------
// proj MFMA GEMM over spikes: Z[t,b,o,n] = sum_c PW[o,c]*S_t[b,c,n].
// Exact 3-way W split (spikes exact in bf16). spkT layout [b][n][c] bytes,
// bit t. Tile 128x128, double-buffered, A async-staged, B bit->bf16 convert.
// ---------------------------------------------------------------------------
__global__ __launch_bounds__(256, 2) void gemm_proj_mfma(
    const u16* __restrict__ Ps, const unsigned char* __restrict__ spkT,
    float* __restrict__ Z)
{
    __shared__ __align__(16) u16 Ab[2][12288];   // 3 splits x 4096
    __shared__ __align__(16) u16 Bb[2][4096];
    const int tid = threadIdx.x;
    const int zb = blockIdx.z, t = zb >> 3, bb = zb & 7;
    const int m0 = blockIdx.y * 128, n0 = blockIdx.x * 128;

    u32 aoff[2][3];
    int lofs[2];
    #pragma unroll
    for (int r = 0; r < 2; r++) {
        const int cid = tid + (r << 8);
        const int mm = cid & 15, kg = (cid >> 4) & 3, mt = cid >> 6;
        lofs[r] = cid * 8;
        #pragma unroll
        for (int s = 0; s < 3; s++)
            aoff[r][s] = (u32)s * 262144u + (u32)(m0 + mt * 16 + mm) * 512u + kg * 8;
    }
    auto stageA = [&](int ki2, int p2) {
        const u32 kk = (u32)ki2 << 5;
        #pragma unroll
        for (int r = 0; r < 2; r++)
            #pragma unroll
            for (int s = 0; s < 3; s++)
                GLD(Ps + aoff[r][s] + kk, &Ab[p2][s * 4096 + lofs[r]]);
    };
    // B: nn = n within 16-tile, ntl = n-tile, seg covers 16 c each
    const int nn = tid & 15, ntl = (tid >> 4) & 7, seg = tid >> 7;
    const u32 srcB = ((u32)bb * 1024u + (u32)(n0 + ntl * 16 + nn)) * 512u + seg * 16;
    const int ldsB0 = (ntl * 64 + seg * 32 + nn) * 8;
    auto convB = [&](uint4 braw, int p2) {
        u32 bs[4] = {braw.x, braw.y, braw.z, braw.w};
        u32 w[8];
        #pragma unroll
        for (int qq = 0; qq < 4; qq++) {
            u32 v = bs[qq] >> t;
            w[qq * 2 + 0] = ((v & 1u) ? 0x3F80u : 0u) | ((v & 0x100u) ? 0x3F800000u : 0u);
            w[qq * 2 + 1] = (((v >> 16) & 1u) ? 0x3F80u : 0u) | ((v & 0x1000000u) ? 0x3F800000u : 0u);
        }
        *(uint4*)&Bb[p2][ldsB0]       = make_uint4(w[0], w[1], w[2], w[3]);
        *(uint4*)&Bb[p2][ldsB0 + 128] = make_uint4(w[4], w[5], w[6], w[7]);
    };

    const int lane = tid & 63, wv = tid >> 6;
    const int wm = wv >> 1, wn = wv & 1;
    const int q = lane >> 4, ln = lane & 15;
    int afo[4], bfo[4];
    #pragma unroll
    for (int i = 0; i < 4; i++) {
        afo[i] = ((wm * 4 + i) * 64 + q * 16 + ln) * 8;
        bfo[i] = ((wn * 4 + i) * 64 + q * 16 + ln) * 8;
    }

    f4v acc[4][4];
    #pragma unroll
    for (int i = 0; i < 4; i++)
        #pragma unroll
        for (int j = 0; j < 4; j++) acc[i][j] = (f4v){0.f, 0.f, 0.f, 0.f};

    stageA(0, 0);
    convB(*(const uint4*)&spkT[srcB], 0);
    uint4 braw;
    for (int ki = 0; ki < 16; ki++) {
        const int p = ki & 1;
        __syncthreads();                 // drains async stage + convB writes
        if (ki < 15) {
            stageA(ki + 1, p ^ 1);
            braw = *(const uint4*)&spkT[srcB + ((u32)(ki + 1) << 5)];
        }
        bf8v bf[4];
        #pragma unroll
        for (int j = 0; j < 4; j++) bf[j] = *(const bf8v*)&Bb[p][bfo[j]];
        #pragma unroll
        for (int sa = 0; sa < 3; sa++) {
            bf8v af[4];
            #pragma unroll
            for (int i = 0; i < 4; i++) af[i] = *(const bf8v*)&Ab[p][sa * 4096 + afo[i]];
            #pragma unroll
            for (int i = 0; i < 4; i++)
                #pragma unroll
                for (int j = 0; j < 4; j++)
                    acc[i][j] = __builtin_amdgcn_mfma_f32_16x16x32_bf16(af[i], bf[j], acc[i][j], 0, 0, 0);
        }
        if (ki < 15) convB(braw, p ^ 1);
    }
    // C/D: col=lane&15, row=(lane>>4)*4+reg  (bias is zero; cancels in BN anyway)
    float* Zb = Z + (size_t)zb * CN;
    #pragma unroll
    for (int i = 0; i < 4; i++) {
        const int row = m0 + (wm * 4 + i) * 16 + q * 4;
        #pragma unroll
        for (int g = 0; g < 4; g++) {
            float* zr = Zb + (size_t)(row + g) * 1024 + n0 + ln;
            #pragma unroll
            for (int j = 0; j < 4; j++)
                zr[(wn * 4 + j) * 16] = acc[i][j][g];
        }
    }
}

// ---------------------------------------------------------------------------
// per-channel mean over (outer, N); X layout [outer][C][N]
// ---------------------------------------------------------------------------
__global__ __launch_bounds__(256) void chan_sum_k(
    const float* __restrict__ X, float* __restrict__ mean, int outer)
{
    __shared__ float red[256];
    const int o = blockIdx.x, tid = threadIdx.x;
    const int total = outer * NDIM;
    float s = 0.f;
    for (int i = tid; i < total; i += 256) {
        int ou = i >> 10, n = i & 1023;
        s += X[(size_t)(ou * C + o) * NDIM + n];
    }
    red[tid] = s; __syncthreads();
    for (int off = 128; off > 0; off >>= 1) {
        if (tid < off) red[tid] += red[tid + off];
        __syncthreads();
    }
    if (tid == 0) mean[o] = red[0] / (float)total;
}

__global__ __launch_bounds__(256) void chan_var_k(
    const float* __restrict__ X, const float* __restrict__ mean,
    float* __restrict__ rstd, int outer)
{
    __shared__ float red[256];
    const int o = blockIdx.x, tid = threadIdx.x;
    const int total = outer * NDIM;
    const float m = mean[o];
    float s = 0.f;
    for (int i = tid; i < total; i += 256) {
        int ou = i >> 10, n = i & 1023;
        float d = X[(size_t)(ou * C + o) * NDIM + n] - m;
        s += d * d;
    }
    red[tid] = s; __syncthreads();
    for (int off = 128; off > 0; off >>= 1) {
        if (tid < off) red[tid] += red[tid + off];
        __syncthreads();
    }
    if (tid == 0) rstd[o] = 1.f / sqrtf(red[0] / (float)total + 1e-5f);
}

// ---------------------------------------------------------------------------
// BN + 4-step LIF (vth=1) on time-constant input -> 4 spike bits per element
// ---------------------------------------------------------------------------
__global__ __launch_bounds__(256) void bn_lif_pack_k(
    const float* __restrict__ Y, const float* __restrict__ mean,
    const float* __restrict__ rstd, const float* __restrict__ gamma,
    const float* __restrict__ beta, unsigned char* __restrict__ spk)
{
    const int idx = blockIdx.x * 256 + threadIdx.x;
    const int o = (idx >> 10) & (C - 1);
    float y = Y[idx];
    float x = gamma[o] * (y - mean[o]);
    x = x * rstd[o] + beta[o];
    float v = 0.f; unsigned bits = 0;
    #pragma unroll
    for (int t = 0; t < 4; t++) {
        v += (x - v) * 0.5f;
        if (v - 1.0f >= 0.f) { bits |= (1u << t); v = 0.f; }
    }
    spk[idx] = (unsigned char)bits;
}

// ---------------------------------------------------------------------------
// Q pack: qm[t][b][h][n] u64, bit dd = spike of channel h*64+dd
// ---------------------------------------------------------------------------
__global__ __launch_bounds__(256) void qpack_k(
    const unsigned char* __restrict__ spk, u64* __restrict__ qm)
{
    __shared__ unsigned char tile[64][80];
    const int tid = threadIdx.x;
    const int bh = blockIdx.x; const int h = bh & 7, b = bh >> 3;
    const int n0 = blockIdx.y * 64;
    {
        int dd = tid >> 2, sg = tid & 3;
        *(uint4*)&tile[dd][sg * 16] =
            *(const uint4*)&spk[(size_t)(b * C + h * 64 + dd) * NDIM + n0 + sg * 16];
    }
    __syncthreads();
    const int lane = tid & 63, wv = tid >> 6;
    for (int i = 0; i < 16; i++) {
        int j = wv * 16 + i;
        unsigned s = tile[lane][j];
        #pragma unroll
        for (int t = 0; t < 4; t++) {
            u64 m = __ballot((s >> t) & 1);
            if (lane == t)
                qm[(size_t)((t * BDIM + b) * HDIM + h) * NDIM + n0 + j] = m;
        }
    }
}

// ---------------------------------------------------------------------------
// K/V pack over n: bits[t][b][c][w] u64
// ---------------------------------------------------------------------------
__global__ __launch_bounds__(256) void kv_pack_k(
    const unsigned char* __restrict__ spk, u64* __restrict__ bits)
{
    const int tid = threadIdx.x;
    const int gw = blockIdx.x * 4 + (tid >> 6);
    const int lane = tid & 63;
    const int w = gw & 15, c = (gw >> 4) & (C - 1), b = gw >> 13;
    unsigned s = spk[(size_t)(b * C + c) * NDIM + w * 64 + lane];
    #pragma unroll
    for (int t = 0; t < 4; t++) {
        u64 m = __ballot((s >> t) & 1);
        if (lane == t)
            bits[(size_t)((t * BDIM + b) * C + c) * 16 + w] = m;
    }
}

// ---------------------------------------------------------------------------
// ktv[t,b,h,dd,e] = popcount(K & V) over bitpacked n (exact)
// ---------------------------------------------------------------------------
__global__ __launch_bounds__(256) void ktv_k(
    const u64* __restrict__ kb, const u64* __restrict__ vb,
    u16* __restrict__ ktv)
{
    __shared__ u64 ks[64][17];
    __shared__ u64 vs[64][17];
    const int tid = threadIdx.x;
    const int g = blockIdx.x;
    const int h = g & 7, b = (g >> 3) & 7, t = g >> 6;
    const size_t base = ((size_t)(t * BDIM + b) * C + h * 64) * 16;
    {
        int r = tid >> 2, w0 = (tid & 3) * 4;
        #pragma unroll
        for (int j = 0; j < 4; j++) {
            ks[r][w0 + j] = kb[base + r * 16 + w0 + j];
            vs[r][w0 + j] = vb[base + r * 16 + w0 + j];
        }
    }
    __syncthreads();
    const int dd = tid >> 2, e0 = (tid & 3) * 16;
    u64 kr[16];
    #pragma unroll
    for (int w = 0; w < 16; w++) kr[w] = ks[dd][w];
    #pragma unroll
    for (int i = 0; i < 16; i++) {
        int e = e0 + i;
        int s = 0;
        #pragma unroll
        for (int w = 0; w < 16; w++) s += __popcll(kr[w] & vs[e][w]);
        ktv[(size_t)(g * 64 + dd) * 64 + e] = (u16)s;
    }
}

// ---------------------------------------------------------------------------
// att + attn LIF (vth=0.5), exact int accumulate; output TRANSPOSED:
// spkT[b][n][c] byte, bit t (layout gemm_proj_mfma stages k-contiguous)
// ---------------------------------------------------------------------------
__global__ __launch_bounds__(256) void att_lif_k(
    const u16* __restrict__ ktv, const u64* __restrict__ qm,
    unsigned char* __restrict__ spkT)
{
    __shared__ u16 ks[4][64][64];
    const int tid = threadIdx.x;
    const int bh = blockIdx.x; const int h = bh & 7, b = bh >> 3;
    const int n0 = blockIdx.y * 64;
    #pragma unroll
    for (int t = 0; t < 4; t++) {
        const u32* src = (const u32*)&ktv[(size_t)((t * BDIM + b) * HDIM + h) * 4096];
        u32* dst = (u32*)&ks[t][0][0];
        #pragma unroll
        for (int j = 0; j < 8; j++) dst[tid + 256 * j] = src[tid + 256 * j];
    }
    __syncthreads();
    const int lane = tid & 63, wv = tid >> 6;
    for (int i = 0; i < 16; i++) {
        const int n = n0 + wv * 16 + i;
        float v = 0.f; unsigned bits = 0;
        #pragma unroll
        for (int t = 0; t < 4; t++) {
            u64 m = qm[(size_t)((t * BDIM + b) * HDIM + h) * NDIM + n];
            int acc = 0;
            while (m) {
                int dd = __ffsll(m) - 1;
                m &= m - 1;
                acc += ks[t][dd][lane];
            }
            float x = (float)acc * 0.125f;
            v += (x - v) * 0.5f;
            if (v - 0.5f >= 0.f) { bits |= (1u << t); v = 0.f; }
        }
        spkT[((size_t)b * 1024 + n) * 512 + h * 64 + lane] = (unsigned char)bits;
    }
}

// ---------------------------------------------------------------------------
// Final BN + LIF (vth=1, time-varying) in place over d_out.
// ---------------------------------------------------------------------------
__global__ __launch_bounds__(256) void final_bn_lif_k(
    float* __restrict__ Z, const float* __restrict__ mean,
    const float* __restrict__ rstd, const float* __restrict__ gamma,
    const float* __restrict__ beta)
{
    const int idx = blockIdx.x * 256 + threadIdx.x;
    const int o = (idx >> 10) & (C - 1);
    const float m = mean[o], rs = rstd[o], g = gamma[o], bt = beta[o];
    float v = 0.f;
    float outs[4];
    #pragma unroll
    for (int t = 0; t < 4; t++) {
        float z = Z[(size_t)t * BCN + idx];
        float x = g * (z - m);
        x = x * rs + bt;
        v += (x - v) * 0.5f;
        float s = (v - 1.0f >= 0.f) ? 1.f : 0.f;
        v *= (1.f - s);
        outs[t] = s;
    }
    #pragma unroll
    for (int t = 0; t < 4; t++) Z[(size_t)t * BCN + idx] = outs[t];
}

// ---------------------------------------------------------------------------
extern "C" void kernel_launch(void* const* d_in, const int* in_sizes, int n_in,
                              void* d_out, int out_size, void* d_ws, size_t ws_size,
                              hipStream_t stream)
{
    const float* q     = (const float*)d_in[0];
    const float* k     = (const float*)d_in[1];
    const float* v     = (const float*)d_in[2];
    const float* W     = (const float*)d_in[3];
    const float* Wb    = (const float*)d_in[4];
    const float* qg    = (const float*)d_in[5];
    const float* qb    = (const float*)d_in[6];
    const float* kg    = (const float*)d_in[7];
    const float* kbt   = (const float*)d_in[8];
    const float* vg    = (const float*)d_in[9];
    const float* vbt   = (const float*)d_in[10];
    const float* pw    = (const float*)d_in[11];
    const float* pg    = (const float*)d_in[13];
    const float* pbeta = (const float*)d_in[14];

    // workspace carve — identical footprint to R1 (~29.1 MB)
    char* p = (char*)d_ws;
    float* Y = (float*)p;                   p += (size_t)BCN * 4;                       // 16.78MB
    unsigned char* spk = (unsigned char*)p; p += (size_t)BCN;                           // 4.19MB
    u64* qmv = (u64*)p;                     p += (size_t)TDIM * BDIM * HDIM * NDIM * 8; // 2MB
    u64* kbits = (u64*)p;                   p += (size_t)TDIM * BDIM * C * 16 * 8;      // 2MB
    u64* vbits = (u64*)p;                   p += (size_t)TDIM * BDIM * C * 16 * 8;      // 2MB
    u16* ktv = (u16*)p;                     p += (size_t)TDIM * BDIM * HDIM * 64 * 64 * 2; // 2.1MB
    float* mean = (float*)p;                p += 4096;
    float* rstd = (float*)p;                p += 4096;

    // Ps (1.57MB) aliases qmv (2MB): qmv is dead after att_lif_k, and
    // split_pw_k launches only after att_lif_k.
    u16* Ps = (u16*)qmv;
    unsigned char* spkT = spk;   // branch spikes dead after kv_pack of br=2
    float* outF = (float*)d_out;

    const float* Xs[3] = {q, k, v};
    const float* Gs[3] = {qg, kg, vg};
    const float* Bt[3] = {qb, kbt, vbt};

    for (int br = 0; br < 3; ++br) {
        gemm_in_k<<<dim3(16, 8, 8), 256, 0, stream>>>(W, Wb, Xs[br], Y, br * C);
        chan_sum_k<<<C, 256, 0, stream>>>(Y, mean, BDIM);
        chan_var_k<<<C, 256, 0, stream>>>(Y, mean, rstd, BDIM);
        bn_lif_pack_k<<<BCN / 256, 256, 0, stream>>>(Y, mean, rstd, Gs[br], Bt[br], spk);
        if (br == 0)
            qpack_k<<<dim3(64, 16), 256, 0, stream>>>(spk, qmv);
        else
            kv_pack_k<<<16384, 256, 0, stream>>>(spk, br == 1 ? kbits : vbits);
    }
    ktv_k<<<256, 256, 0, stream>>>(kbits, vbits, ktv);
    att_lif_k<<<dim3(64, 16), 256, 0, stream>>>(ktv, qmv, spkT);
    split_pw_k<<<1024, 256, 0, stream>>>(pw, Ps);
    gemm_proj_mfma<<<dim3(8, 4, 32), 256, 0, stream>>>(Ps, spkT, outF);
    chan_sum_k<<<C, 256, 0, stream>>>(outF, mean, TDIM * BDIM);
    chan_var_k<<<C, 256, 0, stream>>>(outF, mean, rstd, TDIM * BDIM);
    final_bn_lif_k<<<BCN / 256, 256, 0, stream>>>(outF, mean, rstd, pg, pbeta);
}

// Round 5
// 585.177 us; speedup vs baseline: 1.3329x; 1.1027x over previous
//
#include <hip/hip_runtime.h>

#define C    512
#define NDIM 1024
#define BDIM 8
#define TDIM 4
#define HDIM 8
#define CN   (C*NDIM)        // 524288
#define BCN  (BDIM*CN)       // 4194304

typedef unsigned short u16;
typedef unsigned int   u32;
typedef unsigned long long u64;
typedef __attribute__((ext_vector_type(8))) short bf8v;   // 8 bf16 (4 VGPR)
typedef __attribute__((ext_vector_type(4))) float f4v;    // 4 fp32 acc

// round-to-nearest-even f32 -> bf16 (finite inputs only)
__device__ __forceinline__ u16 f2bf(float f) {
    u32 u = __float_as_uint(f);
    u32 r = u + 0x7FFFu + ((u >> 16) & 1u);
    return (u16)(r >> 16);
}
__device__ __forceinline__ float bf2f(u16 h) { return __uint_as_float((u32)h << 16); }

#if defined(__has_builtin)
#if __has_builtin(__builtin_amdgcn_global_load_lds)
#define HAS_GLL 1
#endif
#endif
#ifdef HAS_GLL
#define GLD(gp, lp) __builtin_amdgcn_global_load_lds( \
    (const __attribute__((address_space(1))) u32*)(gp), \
    (__attribute__((address_space(3))) u32*)(lp), 16, 0, 0)
#else
#define GLD(gp, lp) (*(uint4*)(lp) = *(const uint4*)(const void*)(gp))
#endif

// ---------------------------------------------------------------------------
// Merged in_proj fp32 GEMM, all 3 branches in one launch, 64m x 128n tile.
// Per-output accumulation is a strictly k-ascending fma chain over the same
// staged values as R1's proven kernel -> bit-identical results.
// grid (8 nblk, 8 mblk, 24 = br*8+b)
// ---------------------------------------------------------------------------
__global__ __launch_bounds__(256) void gemm_in3_k(
    const float* __restrict__ W, const float* __restrict__ bias,
    const float* __restrict__ Xq, const float* __restrict__ Xk,
    const float* __restrict__ Xv, float* __restrict__ Y3)
{
    __shared__ float As[16][68];    // [k][m]
    __shared__ float Bs[16][136];   // [k][n]
    const int tid = threadIdx.x;
    const int bz = blockIdx.z;               // br*8 + b
    const int br = bz >> 3, b = bz & 7;
    const int m0 = blockIdx.y * 64;
    const int n0 = blockIdx.x * 128;
    const float* Xb = (br == 0 ? Xq : (br == 1 ? Xk : Xv)) + (size_t)b * CN;
    const int rowOff = br * 512;

    const int am = tid >> 2;        // 0..63  A row (m)
    const int ak = (tid & 3) * 4;   // A col (k)
    const int bk = tid >> 4;        // 0..15  B row (k)
    const int bn = (tid & 15) * 8;  // 0..120 B col (n)
    const int tx = tid & 15, ty = tid >> 4;

    float acc[4][8];
    #pragma unroll
    for (int i = 0; i < 4; i++)
        #pragma unroll
        for (int j = 0; j < 8; j++) acc[i][j] = 0.f;

    for (int k0 = 0; k0 < 512; k0 += 16) {
        float4 a  = *(const float4*)&W [(size_t)(rowOff + m0 + am) * 512 + k0 + ak];
        float4 b0 = *(const float4*)&Xb[(size_t)(k0 + bk) * NDIM + n0 + bn];
        float4 b1 = *(const float4*)&Xb[(size_t)(k0 + bk) * NDIM + n0 + bn + 4];
        __syncthreads();
        As[ak + 0][am] = a.x; As[ak + 1][am] = a.y;
        As[ak + 2][am] = a.z; As[ak + 3][am] = a.w;
        *(float4*)&Bs[bk][bn]     = b0;
        *(float4*)&Bs[bk][bn + 4] = b1;
        __syncthreads();
        #pragma unroll
        for (int k = 0; k < 16; k++) {
            float av[4], bv[8];
            *(float4*)av = *(const float4*)&As[k][ty * 4];
            *(float4*)&bv[0] = *(const float4*)&Bs[k][tx * 8];
            *(float4*)&bv[4] = *(const float4*)&Bs[k][tx * 8 + 4];
            #pragma unroll
            for (int i = 0; i < 4; i++)
                #pragma unroll
                for (int j = 0; j < 8; j++)
                    acc[i][j] += av[i] * bv[j];
        }
    }
    #pragma unroll
    for (int i = 0; i < 4; i++) {
        float bsv = bias[rowOff + m0 + ty * 4 + i];
        float* yr = Y3 + (size_t)bz * CN + (size_t)(m0 + ty * 4 + i) * NDIM + n0 + tx * 8;
        float4 o0 = make_float4(acc[i][0] + bsv, acc[i][1] + bsv,
                                acc[i][2] + bsv, acc[i][3] + bsv);
        float4 o1 = make_float4(acc[i][4] + bsv, acc[i][5] + bsv,
                                acc[i][6] + bsv, acc[i][7] + bsv);
        *(float4*)&yr[0] = o0;
        *(float4*)&yr[4] = o1;
    }
}

// ---------------------------------------------------------------------------
// Split PW (512x512) into exact 3-way bf16 planes.  (R3-proven)
// ---------------------------------------------------------------------------
__global__ __launch_bounds__(256) void split_pw_k(
    const float* __restrict__ PW, u16* __restrict__ Ps)
{
    const int idx = blockIdx.x * 256 + threadIdx.x;   // 512*512 = 262144
    float x = PW[idx];
    u16 h1 = f2bf(x); float r1 = x - bf2f(h1);
    u16 h2 = f2bf(r1); float r2 = r1 - bf2f(h2);
    u16 h3 = f2bf(r2);
    Ps[idx] = h1; Ps[idx + 262144] = h2; Ps[idx + 2 * 262144] = h3;
}

// ---------------------------------------------------------------------------
// proj MFMA GEMM over spikes (R3-proven): Z[t,b,o,n] = sum_c PW[o,c]*S_t[b,c,n]
// ---------------------------------------------------------------------------
__global__ __launch_bounds__(256, 2) void gemm_proj_mfma(
    const u16* __restrict__ Ps, const unsigned char* __restrict__ spkT,
    float* __restrict__ Z)
{
    __shared__ __align__(16) u16 Ab[2][12288];   // 3 splits x 4096
    __shared__ __align__(16) u16 Bb[2][4096];
    const int tid = threadIdx.x;
    const int zb = blockIdx.z, t = zb >> 3, bb = zb & 7;
    const int m0 = blockIdx.y * 128, n0 = blockIdx.x * 128;

    u32 aoff[2][3];
    int lofs[2];
    #pragma unroll
    for (int r = 0; r < 2; r++) {
        const int cid = tid + (r << 8);
        const int mm = cid & 15, kg = (cid >> 4) & 3, mt = cid >> 6;
        lofs[r] = cid * 8;
        #pragma unroll
        for (int s = 0; s < 3; s++)
            aoff[r][s] = (u32)s * 262144u + (u32)(m0 + mt * 16 + mm) * 512u + kg * 8;
    }
    auto stageA = [&](int ki2, int p2) {
        const u32 kk = (u32)ki2 << 5;
        #pragma unroll
        for (int r = 0; r < 2; r++)
            #pragma unroll
            for (int s = 0; s < 3; s++)
                GLD(Ps + aoff[r][s] + kk, &Ab[p2][s * 4096 + lofs[r]]);
    };
    const int nn = tid & 15, ntl = (tid >> 4) & 7, seg = tid >> 7;
    const u32 srcB = ((u32)bb * 1024u + (u32)(n0 + ntl * 16 + nn)) * 512u + seg * 16;
    const int ldsB0 = (ntl * 64 + seg * 32 + nn) * 8;
    auto convB = [&](uint4 braw, int p2) {
        u32 bs[4] = {braw.x, braw.y, braw.z, braw.w};
        u32 w[8];
        #pragma unroll
        for (int qq = 0; qq < 4; qq++) {
            u32 v = bs[qq] >> t;
            w[qq * 2 + 0] = ((v & 1u) ? 0x3F80u : 0u) | ((v & 0x100u) ? 0x3F800000u : 0u);
            w[qq * 2 + 1] = (((v >> 16) & 1u) ? 0x3F80u : 0u) | ((v & 0x1000000u) ? 0x3F800000u : 0u);
        }
        *(uint4*)&Bb[p2][ldsB0]       = make_uint4(w[0], w[1], w[2], w[3]);
        *(uint4*)&Bb[p2][ldsB0 + 128] = make_uint4(w[4], w[5], w[6], w[7]);
    };

    const int lane = tid & 63, wv = tid >> 6;
    const int wm = wv >> 1, wn = wv & 1;
    const int q = lane >> 4, ln = lane & 15;
    int afo[4], bfo[4];
    #pragma unroll
    for (int i = 0; i < 4; i++) {
        afo[i] = ((wm * 4 + i) * 64 + q * 16 + ln) * 8;
        bfo[i] = ((wn * 4 + i) * 64 + q * 16 + ln) * 8;
    }

    f4v acc[4][4];
    #pragma unroll
    for (int i = 0; i < 4; i++)
        #pragma unroll
        for (int j = 0; j < 4; j++) acc[i][j] = (f4v){0.f, 0.f, 0.f, 0.f};

    stageA(0, 0);
    convB(*(const uint4*)&spkT[srcB], 0);
    uint4 braw;
    for (int ki = 0; ki < 16; ki++) {
        const int p = ki & 1;
        __syncthreads();
        if (ki < 15) {
            stageA(ki + 1, p ^ 1);
            braw = *(const uint4*)&spkT[srcB + ((u32)(ki + 1) << 5)];
        }
        bf8v bf[4];
        #pragma unroll
        for (int j = 0; j < 4; j++) bf[j] = *(const bf8v*)&Bb[p][bfo[j]];
        #pragma unroll
        for (int sa = 0; sa < 3; sa++) {
            bf8v af[4];
            #pragma unroll
            for (int i = 0; i < 4; i++) af[i] = *(const bf8v*)&Ab[p][sa * 4096 + afo[i]];
            #pragma unroll
            for (int i = 0; i < 4; i++)
                #pragma unroll
                for (int j = 0; j < 4; j++)
                    acc[i][j] = __builtin_amdgcn_mfma_f32_16x16x32_bf16(af[i], bf[j], acc[i][j], 0, 0, 0);
        }
        if (ki < 15) convB(braw, p ^ 1);
    }
    float* Zb = Z + (size_t)zb * CN;
    #pragma unroll
    for (int i = 0; i < 4; i++) {
        const int row = m0 + (wm * 4 + i) * 16 + q * 4;
        #pragma unroll
        for (int g = 0; g < 4; g++) {
            float* zr = Zb + (size_t)(row + g) * 1024 + n0 + ln;
            #pragma unroll
            for (int j = 0; j < 4; j++)
                zr[(wn * 4 + j) * 16] = acc[i][j][g];
        }
    }
}

// ---------------------------------------------------------------------------
// Per-channel mean, grouped: grid = ngrp*512 blocks; group g = blockIdx>>9
// reads X3 + g*BCN. Body identical to R1-proven chan_sum_k -> bit-exact.
// ---------------------------------------------------------------------------
__global__ __launch_bounds__(256) void chan_sum3_k(
    const float* __restrict__ X3, float* __restrict__ mean3, int outer)
{
    __shared__ float red[256];
    const int gb = blockIdx.x;
    const int o = gb & (C - 1);
    const float* X = X3 + (size_t)(gb >> 9) * BCN;
    const int tid = threadIdx.x;
    const int total = outer * NDIM;
    float s = 0.f;
    for (int i = tid; i < total; i += 256) {
        int ou = i >> 10, n = i & 1023;
        s += X[(size_t)(ou * C + o) * NDIM + n];
    }
    red[tid] = s; __syncthreads();
    for (int off = 128; off > 0; off >>= 1) {
        if (tid < off) red[tid] += red[tid + off];
        __syncthreads();
    }
    if (tid == 0) mean3[gb] = red[0] / (float)total;
}

__global__ __launch_bounds__(256) void chan_var3_k(
    const float* __restrict__ X3, const float* __restrict__ mean3,
    float* __restrict__ rstd3, int outer)
{
    __shared__ float red[256];
    const int gb = blockIdx.x;
    const int o = gb & (C - 1);
    const float* X = X3 + (size_t)(gb >> 9) * BCN;
    const int tid = threadIdx.x;
    const int total = outer * NDIM;
    const float m = mean3[gb];
    float s = 0.f;
    for (int i = tid; i < total; i += 256) {
        int ou = i >> 10, n = i & 1023;
        float d = X[(size_t)(ou * C + o) * NDIM + n] - m;
        s += d * d;
    }
    red[tid] = s; __syncthreads();
    for (int off = 128; off > 0; off >>= 1) {
        if (tid < off) red[tid] += red[tid + off];
        __syncthreads();
    }
    if (tid == 0) rstd3[gb] = 1.f / sqrtf(red[0] / (float)total + 1e-5f);
}

// ---------------------------------------------------------------------------
// BN + 4-step LIF (vth=1) -> spike byte per element  (R3-proven)
// ---------------------------------------------------------------------------
__global__ __launch_bounds__(256) void bn_lif_pack_k(
    const float* __restrict__ Y, const float* __restrict__ mean,
    const float* __restrict__ rstd, const float* __restrict__ gamma,
    const float* __restrict__ beta, unsigned char* __restrict__ spk)
{
    const int idx = blockIdx.x * 256 + threadIdx.x;
    const int o = (idx >> 10) & (C - 1);
    float y = Y[idx];
    float x = gamma[o] * (y - mean[o]);
    x = x * rstd[o] + beta[o];
    float v = 0.f; unsigned bits = 0;
    #pragma unroll
    for (int t = 0; t < 4; t++) {
        v += (x - v) * 0.5f;
        if (v - 1.0f >= 0.f) { bits |= (1u << t); v = 0.f; }
    }
    spk[idx] = (unsigned char)bits;
}

// ---------------------------------------------------------------------------
// Q pack: qm[t][b][h][n] u64, bit dd = spike of channel h*64+dd  (R3-proven)
// ---------------------------------------------------------------------------
__global__ __launch_bounds__(256) void qpack_k(
    const unsigned char* __restrict__ spk, u64* __restrict__ qm)
{
    __shared__ unsigned char tile[64][80];
    const int tid = threadIdx.x;
    const int bh = blockIdx.x; const int h = bh & 7, b = bh >> 3;
    const int n0 = blockIdx.y * 64;
    {
        int dd = tid >> 2, sg = tid & 3;
        *(uint4*)&tile[dd][sg * 16] =
            *(const uint4*)&spk[(size_t)(b * C + h * 64 + dd) * NDIM + n0 + sg * 16];
    }
    __syncthreads();
    const int lane = tid & 63, wv = tid >> 6;
    for (int i = 0; i < 16; i++) {
        int j = wv * 16 + i;
        unsigned s = tile[lane][j];
        #pragma unroll
        for (int t = 0; t < 4; t++) {
            u64 m = __ballot((s >> t) & 1);
            if (lane == t)
                qm[(size_t)((t * BDIM + b) * HDIM + h) * NDIM + n0 + j] = m;
        }
    }
}

// ---------------------------------------------------------------------------
// K/V pack over n: bits[t][b][c][w] u64  (R3-proven)
// ---------------------------------------------------------------------------
__global__ __launch_bounds__(256) void kv_pack_k(
    const unsigned char* __restrict__ spk, u64* __restrict__ bits)
{
    const int tid = threadIdx.x;
    const int gw = blockIdx.x * 4 + (tid >> 6);
    const int lane = tid & 63;
    const int w = gw & 15, c = (gw >> 4) & (C - 1), b = gw >> 13;
    unsigned s = spk[(size_t)(b * C + c) * NDIM + w * 64 + lane];
    #pragma unroll
    for (int t = 0; t < 4; t++) {
        u64 m = __ballot((s >> t) & 1);
        if (lane == t)
            bits[(size_t)((t * BDIM + b) * C + c) * 16 + w] = m;
    }
}

// ---------------------------------------------------------------------------
// ktv[t,b,h,dd,e] = popcount(K & V) over bitpacked n (exact)  (R3-proven)
// ---------------------------------------------------------------------------
__global__ __launch_bounds__(256) void ktv_k(
    const u64* __restrict__ kb, const u64* __restrict__ vb,
    u16* __restrict__ ktv)
{
    __shared__ u64 ks[64][17];
    __shared__ u64 vs[64][17];
    const int tid = threadIdx.x;
    const int g = blockIdx.x;
    const int h = g & 7, b = (g >> 3) & 7, t = g >> 6;
    const size_t base = ((size_t)(t * BDIM + b) * C + h * 64) * 16;
    {
        int r = tid >> 2, w0 = (tid & 3) * 4;
        #pragma unroll
        for (int j = 0; j < 4; j++) {
            ks[r][w0 + j] = kb[base + r * 16 + w0 + j];
            vs[r][w0 + j] = vb[base + r * 16 + w0 + j];
        }
    }
    __syncthreads();
    const int dd = tid >> 2, e0 = (tid & 3) * 16;
    u64 kr[16];
    #pragma unroll
    for (int w = 0; w < 16; w++) kr[w] = ks[dd][w];
    #pragma unroll
    for (int i = 0; i < 16; i++) {
        int e = e0 + i;
        int s = 0;
        #pragma unroll
        for (int w = 0; w < 16; w++) s += __popcll(kr[w] & vs[e][w]);
        ktv[(size_t)(g * 64 + dd) * 64 + e] = (u16)s;
    }
}

// ---------------------------------------------------------------------------
// att + attn LIF (vth=0.5); output transposed spkT[b][n][c], bit t (R3-proven)
// ---------------------------------------------------------------------------
__global__ __launch_bounds__(256) void att_lif_k(
    const u16* __restrict__ ktv, const u64* __restrict__ qm,
    unsigned char* __restrict__ spkT)
{
    __shared__ u16 ks[4][64][64];
    const int tid = threadIdx.x;
    const int bh = blockIdx.x; const int h = bh & 7, b = bh >> 3;
    const int n0 = blockIdx.y * 64;
    #pragma unroll
    for (int t = 0; t < 4; t++) {
        const u32* src = (const u32*)&ktv[(size_t)((t * BDIM + b) * HDIM + h) * 4096];
        u32* dst = (u32*)&ks[t][0][0];
        #pragma unroll
        for (int j = 0; j < 8; j++) dst[tid + 256 * j] = src[tid + 256 * j];
    }
    __syncthreads();
    const int lane = tid & 63, wv = tid >> 6;
    for (int i = 0; i < 16; i++) {
        const int n = n0 + wv * 16 + i;
        float v = 0.f; unsigned bits = 0;
        #pragma unroll
        for (int t = 0; t < 4; t++) {
            u64 m = qm[(size_t)((t * BDIM + b) * HDIM + h) * NDIM + n];
            int acc = 0;
            while (m) {
                int dd = __ffsll(m) - 1;
                m &= m - 1;
                acc += ks[t][dd][lane];
            }
            float x = (float)acc * 0.125f;
            v += (x - v) * 0.5f;
            if (v - 0.5f >= 0.f) { bits |= (1u << t); v = 0.f; }
        }
        spkT[((size_t)b * 1024 + n) * 512 + h * 64 + lane] = (unsigned char)bits;
    }
}

// ---------------------------------------------------------------------------
// Final BN + LIF (vth=1, time-varying) in place over d_out.  (R3-proven)
// ---------------------------------------------------------------------------
__global__ __launch_bounds__(256) void final_bn_lif_k(
    float* __restrict__ Z, const float* __restrict__ mean,
    const float* __restrict__ rstd, const float* __restrict__ gamma,
    const float* __restrict__ beta)
{
    const int idx = blockIdx.x * 256 + threadIdx.x;
    const int o = (idx >> 10) & (C - 1);
    const float m = mean[o], rs = rstd[o], g = gamma[o], bt = beta[o];
    float v = 0.f;
    float outs[4];
    #pragma unroll
    for (int t = 0; t < 4; t++) {
        float z = Z[(size_t)t * BCN + idx];
        float x = g * (z - m);
        x = x * rs + bt;
        v += (x - v) * 0.5f;
        float s = (v - 1.0f >= 0.f) ? 1.f : 0.f;
        v *= (1.f - s);
        outs[t] = s;
    }
    #pragma unroll
    for (int t = 0; t < 4; t++) Z[(size_t)t * BCN + idx] = outs[t];
}

// ---------------------------------------------------------------------------
extern "C" void kernel_launch(void* const* d_in, const int* in_sizes, int n_in,
                              void* d_out, int out_size, void* d_ws, size_t ws_size,
                              hipStream_t stream)
{
    const float* q     = (const float*)d_in[0];
    const float* k     = (const float*)d_in[1];
    const float* v     = (const float*)d_in[2];
    const float* W     = (const float*)d_in[3];
    const float* Wb    = (const float*)d_in[4];
    const float* qg    = (const float*)d_in[5];
    const float* qb    = (const float*)d_in[6];
    const float* kg    = (const float*)d_in[7];
    const float* kbt   = (const float*)d_in[8];
    const float* vg    = (const float*)d_in[9];
    const float* vbt   = (const float*)d_in[10];
    const float* pw    = (const float*)d_in[11];
    const float* pg    = (const float*)d_in[13];
    const float* pbeta = (const float*)d_in[14];

    // workspace carve (~12.3 MB; Y moved into d_out)
    char* p = (char*)d_ws;
    unsigned char* spk = (unsigned char*)p; p += (size_t)BCN;                           // 4.19MB
    u64* qmv = (u64*)p;                     p += (size_t)TDIM * BDIM * HDIM * NDIM * 8; // 2MB
    u64* kbits = (u64*)p;                   p += (size_t)TDIM * BDIM * C * 16 * 8;      // 2MB
    u64* vbits = (u64*)p;                   p += (size_t)TDIM * BDIM * C * 16 * 8;      // 2MB
    u16* ktv = (u16*)p;                     p += (size_t)TDIM * BDIM * HDIM * 64 * 64 * 2; // 2.1MB
    float* mean3 = (float*)p;               p += 8192;   // 1536 used
    float* rstd3 = (float*)p;               p += 8192;

    // d_out scratch: Y3 = [br][b][C][N] fp32 (50.3MB of 67.1MB), dead before
    // gemm_proj overwrites d_out with Z.
    float* Y3 = (float*)d_out;
    float* outF = (float*)d_out;
    u16* Ps = (u16*)qmv;         // qmv dead after att_lif_k; split_pw after it
    unsigned char* spkT = spk;   // branch spike bytes dead after packs

    const float* Gs[3] = {qg, kg, vg};
    const float* Bt[3] = {qb, kbt, vbt};

    gemm_in3_k<<<dim3(8, 8, 24), 256, 0, stream>>>(W, Wb, q, k, v, Y3);
    chan_sum3_k<<<3 * C, 256, 0, stream>>>(Y3, mean3, BDIM);
    chan_var3_k<<<3 * C, 256, 0, stream>>>(Y3, mean3, rstd3, BDIM);
    for (int br = 0; br < 3; ++br) {
        bn_lif_pack_k<<<BCN / 256, 256, 0, stream>>>(Y3 + (size_t)br * BCN,
            mean3 + br * C, rstd3 + br * C, Gs[br], Bt[br], spk);
        if (br == 0)
            qpack_k<<<dim3(64, 16), 256, 0, stream>>>(spk, qmv);
        else
            kv_pack_k<<<16384, 256, 0, stream>>>(spk, br == 1 ? kbits : vbits);
    }
    ktv_k<<<256, 256, 0, stream>>>(kbits, vbits, ktv);
    att_lif_k<<<dim3(64, 16), 256, 0, stream>>>(ktv, qmv, spkT);
    split_pw_k<<<1024, 256, 0, stream>>>(pw, Ps);
    gemm_proj_mfma<<<dim3(8, 4, 32), 256, 0, stream>>>(Ps, spkT, outF);
    chan_sum3_k<<<C, 256, 0, stream>>>(outF, mean3, TDIM * BDIM);
    chan_var3_k<<<C, 256, 0, stream>>>(outF, mean3, rstd3, TDIM * BDIM);
    final_bn_lif_k<<<BCN / 256, 256, 0, stream>>>(outF, mean3, rstd3, pg, pbeta);
}

// Round 6
// 553.419 us; speedup vs baseline: 1.4094x; 1.0574x over previous
//
#include <hip/hip_runtime.h>

#define C    512
#define NDIM 1024
#define BDIM 8
#define TDIM 4
#define HDIM 8
#define CN   (C*NDIM)        // 524288
#define BCN  (BDIM*CN)       // 4194304

typedef unsigned short u16;
typedef unsigned int   u32;
typedef unsigned long long u64;
typedef __attribute__((ext_vector_type(8))) short bf8v;   // 8 bf16 (4 VGPR)
typedef __attribute__((ext_vector_type(4))) float f4v;    // 4 fp32 acc

// round-to-nearest-even f32 -> bf16 (finite inputs only)
__device__ __forceinline__ u16 f2bf(float f) {
    u32 u = __float_as_uint(f);
    u32 r = u + 0x7FFFu + ((u >> 16) & 1u);
    return (u16)(r >> 16);
}
__device__ __forceinline__ float bf2f(u16 h) { return __uint_as_float((u32)h << 16); }

#if defined(__has_builtin)
#if __has_builtin(__builtin_amdgcn_global_load_lds)
#define HAS_GLL 1
#endif
#endif
#ifdef HAS_GLL
#define GLD(gp, lp) __builtin_amdgcn_global_load_lds( \
    (const __attribute__((address_space(1))) u32*)(gp), \
    (__attribute__((address_space(3))) u32*)(lp), 16, 0, 0)
#else
#define GLD(gp, lp) (*(uint4*)(lp) = *(const uint4*)(const void*)(gp))
#endif

// ---------------------------------------------------------------------------
// Merged in_proj fp32 GEMM, 128m x 128n tile, conflict-free LDS mappings.
// Per-output accumulation is the same strictly k-ascending fma chain over the
// same staged values as the R1/R5-proven kernels -> bit-identical Y.
// Micro-tile: 4x4 quadrants at rows ty*4+{0,64}, cols tx*4+{0,64}
// (16B lane stride -> 2-way bank aliasing = free).
// grid (8 nblk, 4 mblk, 24 = br*8+b)
// ---------------------------------------------------------------------------
__global__ __launch_bounds__(256) void gemm_in3_k(
    const float* __restrict__ W, const float* __restrict__ bias,
    const float* __restrict__ Xq, const float* __restrict__ Xk,
    const float* __restrict__ Xv, float* __restrict__ Y3)
{
    __shared__ float As[16][132];   // [k][m], pad 132
    __shared__ float Bs[16][132];   // [k][n]
    const int tid = threadIdx.x;
    const int bz = blockIdx.z;               // br*8 + b
    const int br = bz >> 3, b = bz & 7;
    const int m0 = blockIdx.y * 128;
    const int n0 = blockIdx.x * 128;
    const float* Xb = (br == 0 ? Xq : (br == 1 ? Xk : Xv)) + (size_t)b * CN;
    const int rowOff = br * 512;

    // A staging: row ra = tid>>2 (+64), ka = (tid&3)*4  (k-contiguous float4)
    const int ra = tid >> 2, ka = (tid & 3) * 4;
    // B staging: kb = tid>>5 (+8), nb = (tid&31)*4      (n-contiguous float4)
    const int kb = tid >> 5, nb = (tid & 31) * 4;
    const int tx = tid & 15, ty = tid >> 4;

    float acc[2][2][4][4];   // [mq][nq][i][j]
    #pragma unroll
    for (int mq = 0; mq < 2; mq++)
        #pragma unroll
        for (int nq = 0; nq < 2; nq++)
            #pragma unroll
            for (int i = 0; i < 4; i++)
                #pragma unroll
                for (int j = 0; j < 4; j++) acc[mq][nq][i][j] = 0.f;

    for (int k0 = 0; k0 < 512; k0 += 16) {
        float4 a0 = *(const float4*)&W[(size_t)(rowOff + m0 + ra) * 512 + k0 + ka];
        float4 a1 = *(const float4*)&W[(size_t)(rowOff + m0 + 64 + ra) * 512 + k0 + ka];
        float4 b0 = *(const float4*)&Xb[(size_t)(k0 + kb) * NDIM + n0 + nb];
        float4 b1 = *(const float4*)&Xb[(size_t)(k0 + 8 + kb) * NDIM + n0 + nb];
        __syncthreads();
        As[ka + 0][ra] = a0.x; As[ka + 1][ra] = a0.y;
        As[ka + 2][ra] = a0.z; As[ka + 3][ra] = a0.w;
        As[ka + 0][64 + ra] = a1.x; As[ka + 1][64 + ra] = a1.y;
        As[ka + 2][64 + ra] = a1.z; As[ka + 3][64 + ra] = a1.w;
        *(float4*)&Bs[kb][nb]     = b0;
        *(float4*)&Bs[kb + 8][nb] = b1;
        __syncthreads();
        #pragma unroll
        for (int k = 0; k < 16; k++) {
            float av[2][4], bv[2][4];
            *(float4*)av[0] = *(const float4*)&As[k][ty * 4];
            *(float4*)av[1] = *(const float4*)&As[k][64 + ty * 4];
            *(float4*)bv[0] = *(const float4*)&Bs[k][tx * 4];
            *(float4*)bv[1] = *(const float4*)&Bs[k][64 + tx * 4];
            #pragma unroll
            for (int mq = 0; mq < 2; mq++)
                #pragma unroll
                for (int nq = 0; nq < 2; nq++)
                    #pragma unroll
                    for (int i = 0; i < 4; i++)
                        #pragma unroll
                        for (int j = 0; j < 4; j++)
                            acc[mq][nq][i][j] += av[mq][i] * bv[nq][j];
        }
    }
    #pragma unroll
    for (int mq = 0; mq < 2; mq++)
        #pragma unroll
        for (int i = 0; i < 4; i++) {
            const int mrow = mq * 64 + ty * 4 + i;
            float bsv = bias[rowOff + m0 + mrow];
            float* yr = Y3 + (size_t)bz * CN + (size_t)(m0 + mrow) * NDIM + n0;
            #pragma unroll
            for (int nq = 0; nq < 2; nq++) {
                float4 o4 = make_float4(acc[mq][nq][i][0] + bsv, acc[mq][nq][i][1] + bsv,
                                        acc[mq][nq][i][2] + bsv, acc[mq][nq][i][3] + bsv);
                *(float4*)&yr[nq * 64 + tx * 4] = o4;
            }
        }
}

// ---------------------------------------------------------------------------
// Split PW (512x512) into exact 3-way bf16 planes.  (R3-proven)
// ---------------------------------------------------------------------------
__global__ __launch_bounds__(256) void split_pw_k(
    const float* __restrict__ PW, u16* __restrict__ Ps)
{
    const int idx = blockIdx.x * 256 + threadIdx.x;   // 512*512 = 262144
    float x = PW[idx];
    u16 h1 = f2bf(x); float r1 = x - bf2f(h1);
    u16 h2 = f2bf(r1); float r2 = r1 - bf2f(h2);
    u16 h3 = f2bf(r2);
    Ps[idx] = h1; Ps[idx + 262144] = h2; Ps[idx + 2 * 262144] = h3;
}

// ---------------------------------------------------------------------------
// proj MFMA GEMM over spikes (R3-proven): Z[t,b,o,n] = sum_c PW[o,c]*S_t[b,c,n]
// ---------------------------------------------------------------------------
__global__ __launch_bounds__(256, 2) void gemm_proj_mfma(
    const u16* __restrict__ Ps, const unsigned char* __restrict__ spkT,
    float* __restrict__ Z)
{
    __shared__ __align__(16) u16 Ab[2][12288];   // 3 splits x 4096
    __shared__ __align__(16) u16 Bb[2][4096];
    const int tid = threadIdx.x;
    const int zb = blockIdx.z, t = zb >> 3, bb = zb & 7;
    const int m0 = blockIdx.y * 128, n0 = blockIdx.x * 128;

    u32 aoff[2][3];
    int lofs[2];
    #pragma unroll
    for (int r = 0; r < 2; r++) {
        const int cid = tid + (r << 8);
        const int mm = cid & 15, kg = (cid >> 4) & 3, mt = cid >> 6;
        lofs[r] = cid * 8;
        #pragma unroll
        for (int s = 0; s < 3; s++)
            aoff[r][s] = (u32)s * 262144u + (u32)(m0 + mt * 16 + mm) * 512u + kg * 8;
    }
    auto stageA = [&](int ki2, int p2) {
        const u32 kk = (u32)ki2 << 5;
        #pragma unroll
        for (int r = 0; r < 2; r++)
            #pragma unroll
            for (int s = 0; s < 3; s++)
                GLD(Ps + aoff[r][s] + kk, &Ab[p2][s * 4096 + lofs[r]]);
    };
    const int nn = tid & 15, ntl = (tid >> 4) & 7, seg = tid >> 7;
    const u32 srcB = ((u32)bb * 1024u + (u32)(n0 + ntl * 16 + nn)) * 512u + seg * 16;
    const int ldsB0 = (ntl * 64 + seg * 32 + nn) * 8;
    auto convB = [&](uint4 braw, int p2) {
        u32 bs[4] = {braw.x, braw.y, braw.z, braw.w};
        u32 w[8];
        #pragma unroll
        for (int qq = 0; qq < 4; qq++) {
            u32 v = bs[qq] >> t;
            w[qq * 2 + 0] = ((v & 1u) ? 0x3F80u : 0u) | ((v & 0x100u) ? 0x3F800000u : 0u);
            w[qq * 2 + 1] = (((v >> 16) & 1u) ? 0x3F80u : 0u) | ((v & 0x1000000u) ? 0x3F800000u : 0u);
        }
        *(uint4*)&Bb[p2][ldsB0]       = make_uint4(w[0], w[1], w[2], w[3]);
        *(uint4*)&Bb[p2][ldsB0 + 128] = make_uint4(w[4], w[5], w[6], w[7]);
    };

    const int lane = tid & 63, wv = tid >> 6;
    const int wm = wv >> 1, wn = wv & 1;
    const int q = lane >> 4, ln = lane & 15;
    int afo[4], bfo[4];
    #pragma unroll
    for (int i = 0; i < 4; i++) {
        afo[i] = ((wm * 4 + i) * 64 + q * 16 + ln) * 8;
        bfo[i] = ((wn * 4 + i) * 64 + q * 16 + ln) * 8;
    }

    f4v acc[4][4];
    #pragma unroll
    for (int i = 0; i < 4; i++)
        #pragma unroll
        for (int j = 0; j < 4; j++) acc[i][j] = (f4v){0.f, 0.f, 0.f, 0.f};

    stageA(0, 0);
    convB(*(const uint4*)&spkT[srcB], 0);
    uint4 braw;
    for (int ki = 0; ki < 16; ki++) {
        const int p = ki & 1;
        __syncthreads();
        if (ki < 15) {
            stageA(ki + 1, p ^ 1);
            braw = *(const uint4*)&spkT[srcB + ((u32)(ki + 1) << 5)];
        }
        bf8v bf[4];
        #pragma unroll
        for (int j = 0; j < 4; j++) bf[j] = *(const bf8v*)&Bb[p][bfo[j]];
        #pragma unroll
        for (int sa = 0; sa < 3; sa++) {
            bf8v af[4];
            #pragma unroll
            for (int i = 0; i < 4; i++) af[i] = *(const bf8v*)&Ab[p][sa * 4096 + afo[i]];
            #pragma unroll
            for (int i = 0; i < 4; i++)
                #pragma unroll
                for (int j = 0; j < 4; j++)
                    acc[i][j] = __builtin_amdgcn_mfma_f32_16x16x32_bf16(af[i], bf[j], acc[i][j], 0, 0, 0);
        }
        if (ki < 15) convB(braw, p ^ 1);
    }
    float* Zb = Z + (size_t)zb * CN;
    #pragma unroll
    for (int i = 0; i < 4; i++) {
        const int row = m0 + (wm * 4 + i) * 16 + q * 4;
        #pragma unroll
        for (int g = 0; g < 4; g++) {
            float* zr = Zb + (size_t)(row + g) * 1024 + n0 + ln;
            #pragma unroll
            for (int j = 0; j < 4; j++)
                zr[(wn * 4 + j) * 16] = acc[i][j][g];
        }
    }
}

// ---------------------------------------------------------------------------
// Per-channel mean, grouped (R5-proven, bit-exact body)
// ---------------------------------------------------------------------------
__global__ __launch_bounds__(256) void chan_sum3_k(
    const float* __restrict__ X3, float* __restrict__ mean3, int outer)
{
    __shared__ float red[256];
    const int gb = blockIdx.x;
    const int o = gb & (C - 1);
    const float* X = X3 + (size_t)(gb >> 9) * BCN;
    const int tid = threadIdx.x;
    const int total = outer * NDIM;
    float s = 0.f;
    for (int i = tid; i < total; i += 256) {
        int ou = i >> 10, n = i & 1023;
        s += X[(size_t)(ou * C + o) * NDIM + n];
    }
    red[tid] = s; __syncthreads();
    for (int off = 128; off > 0; off >>= 1) {
        if (tid < off) red[tid] += red[tid + off];
        __syncthreads();
    }
    if (tid == 0) mean3[gb] = red[0] / (float)total;
}

__global__ __launch_bounds__(256) void chan_var3_k(
    const float* __restrict__ X3, const float* __restrict__ mean3,
    float* __restrict__ rstd3, int outer)
{
    __shared__ float red[256];
    const int gb = blockIdx.x;
    const int o = gb & (C - 1);
    const float* X = X3 + (size_t)(gb >> 9) * BCN;
    const int tid = threadIdx.x;
    const int total = outer * NDIM;
    const float m = mean3[gb];
    float s = 0.f;
    for (int i = tid; i < total; i += 256) {
        int ou = i >> 10, n = i & 1023;
        float d = X[(size_t)(ou * C + o) * NDIM + n] - m;
        s += d * d;
    }
    red[tid] = s; __syncthreads();
    for (int off = 128; off > 0; off >>= 1) {
        if (tid < off) red[tid] += red[tid + off];
        __syncthreads();
    }
    if (tid == 0) rstd3[gb] = 1.f / sqrtf(red[0] / (float)total + 1e-5f);
}

// ---------------------------------------------------------------------------
// BN + 4-step LIF (vth=1) -> spike byte per element  (Q branch; R3-proven)
// ---------------------------------------------------------------------------
__global__ __launch_bounds__(256) void bn_lif_pack_k(
    const float* __restrict__ Y, const float* __restrict__ mean,
    const float* __restrict__ rstd, const float* __restrict__ gamma,
    const float* __restrict__ beta, unsigned char* __restrict__ spk)
{
    const int idx = blockIdx.x * 256 + threadIdx.x;
    const int o = (idx >> 10) & (C - 1);
    float y = Y[idx];
    float x = gamma[o] * (y - mean[o]);
    x = x * rstd[o] + beta[o];
    float v = 0.f; unsigned bits = 0;
    #pragma unroll
    for (int t = 0; t < 4; t++) {
        v += (x - v) * 0.5f;
        if (v - 1.0f >= 0.f) { bits |= (1u << t); v = 0.f; }
    }
    spk[idx] = (unsigned char)bits;
}

// ---------------------------------------------------------------------------
// K/V branches: BN + LIF + ballot-bitpack fused. Spike bits are identical to
// bn_lif_pack_k's (same arithmetic); only the packing differs -> bit-exact.
// bits[t][b][c][w] u64, bit j = spike at n = w*64+j.
// ---------------------------------------------------------------------------
__global__ __launch_bounds__(256) void bn_lif_kv_k(
    const float* __restrict__ Y, const float* __restrict__ mean,
    const float* __restrict__ rstd, const float* __restrict__ gamma,
    const float* __restrict__ beta, u64* __restrict__ bits)
{
    const int idx = blockIdx.x * 256 + threadIdx.x;   // (b,c,n) flat over BCN
    const int o = (idx >> 10) & (C - 1);
    const int b = idx >> 19;
    const int n = idx & 1023;
    float y = Y[idx];
    float x = gamma[o] * (y - mean[o]);
    x = x * rstd[o] + beta[o];
    float v = 0.f; unsigned sb = 0;
    #pragma unroll
    for (int t = 0; t < 4; t++) {
        v += (x - v) * 0.5f;
        if (v - 1.0f >= 0.f) { sb |= (1u << t); v = 0.f; }
    }
    const int lane = threadIdx.x & 63;
    #pragma unroll
    for (int t = 0; t < 4; t++) {
        u64 m = __ballot((sb >> t) & 1);
        if (lane == t)
            bits[((size_t)(t * BDIM + b) * C + o) * 16 + (n >> 6)] = m;
    }
}

// ---------------------------------------------------------------------------
// Q pack: qm[t][b][h][n] u64, bit dd = spike of channel h*64+dd  (R3-proven)
// ---------------------------------------------------------------------------
__global__ __launch_bounds__(256) void qpack_k(
    const unsigned char* __restrict__ spk, u64* __restrict__ qm)
{
    __shared__ unsigned char tile[64][80];
    const int tid = threadIdx.x;
    const int bh = blockIdx.x; const int h = bh & 7, b = bh >> 3;
    const int n0 = blockIdx.y * 64;
    {
        int dd = tid >> 2, sg = tid & 3;
        *(uint4*)&tile[dd][sg * 16] =
            *(const uint4*)&spk[(size_t)(b * C + h * 64 + dd) * NDIM + n0 + sg * 16];
    }
    __syncthreads();
    const int lane = tid & 63, wv = tid >> 6;
    for (int i = 0; i < 16; i++) {
        int j = wv * 16 + i;
        unsigned s = tile[lane][j];
        #pragma unroll
        for (int t = 0; t < 4; t++) {
            u64 m = __ballot((s >> t) & 1);
            if (lane == t)
                qm[(size_t)((t * BDIM + b) * HDIM + h) * NDIM + n0 + j] = m;
        }
    }
}

// ---------------------------------------------------------------------------
// ktv[t,b,h,dd,e] = popcount(K & V) over bitpacked n (exact)  (R3-proven)
// ---------------------------------------------------------------------------
__global__ __launch_bounds__(256) void ktv_k(
    const u64* __restrict__ kb, const u64* __restrict__ vb,
    u16* __restrict__ ktv)
{
    __shared__ u64 ks[64][17];
    __shared__ u64 vs[64][17];
    const int tid = threadIdx.x;
    const int g = blockIdx.x;
    const int h = g & 7, b = (g >> 3) & 7, t = g >> 6;
    const size_t base = ((size_t)(t * BDIM + b) * C + h * 64) * 16;
    {
        int r = tid >> 2, w0 = (tid & 3) * 4;
        #pragma unroll
        for (int j = 0; j < 4; j++) {
            ks[r][w0 + j] = kb[base + r * 16 + w0 + j];
            vs[r][w0 + j] = vb[base + r * 16 + w0 + j];
        }
    }
    __syncthreads();
    const int dd = tid >> 2, e0 = (tid & 3) * 16;
    u64 kr[16];
    #pragma unroll
    for (int w = 0; w < 16; w++) kr[w] = ks[dd][w];
    #pragma unroll
    for (int i = 0; i < 16; i++) {
        int e = e0 + i;
        int s = 0;
        #pragma unroll
        for (int w = 0; w < 16; w++) s += __popcll(kr[w] & vs[e][w]);
        ktv[(size_t)(g * 64 + dd) * 64 + e] = (u16)s;
    }
}

// ---------------------------------------------------------------------------
// att + attn LIF (vth=0.5); output transposed spkT[b][n][c], bit t (R3-proven)
// ---------------------------------------------------------------------------
__global__ __launch_bounds__(256) void att_lif_k(
    const u16* __restrict__ ktv, const u64* __restrict__ qm,
    unsigned char* __restrict__ spkT)
{
    __shared__ u16 ks[4][64][64];
    const int tid = threadIdx.x;
    const int bh = blockIdx.x; const int h = bh & 7, b = bh >> 3;
    const int n0 = blockIdx.y * 64;
    #pragma unroll
    for (int t = 0; t < 4; t++) {
        const u32* src = (const u32*)&ktv[(size_t)((t * BDIM + b) * HDIM + h) * 4096];
        u32* dst = (u32*)&ks[t][0][0];
        #pragma unroll
        for (int j = 0; j < 8; j++) dst[tid + 256 * j] = src[tid + 256 * j];
    }
    __syncthreads();
    const int lane = tid & 63, wv = tid >> 6;
    for (int i = 0; i < 16; i++) {
        const int n = n0 + wv * 16 + i;
        float v = 0.f; unsigned bits = 0;
        #pragma unroll
        for (int t = 0; t < 4; t++) {
            u64 m = qm[(size_t)((t * BDIM + b) * HDIM + h) * NDIM + n];
            int acc = 0;
            while (m) {
                int dd = __ffsll(m) - 1;
                m &= m - 1;
                acc += ks[t][dd][lane];
            }
            float x = (float)acc * 0.125f;
            v += (x - v) * 0.5f;
            if (v - 0.5f >= 0.f) { bits |= (1u << t); v = 0.f; }
        }
        spkT[((size_t)b * 1024 + n) * 512 + h * 64 + lane] = (unsigned char)bits;
    }
}

// ---------------------------------------------------------------------------
// Final BN + LIF (vth=1, time-varying) in place over d_out.  (R3-proven)
// ---------------------------------------------------------------------------
__global__ __launch_bounds__(256) void final_bn_lif_k(
    float* __restrict__ Z, const float* __restrict__ mean,
    const float* __restrict__ rstd, const float* __restrict__ gamma,
    const float* __restrict__ beta)
{
    const int idx = blockIdx.x * 256 + threadIdx.x;
    const int o = (idx >> 10) & (C - 1);
    const float m = mean[o], rs = rstd[o], g = gamma[o], bt = beta[o];
    float v = 0.f;
    float outs[4];
    #pragma unroll
    for (int t = 0; t < 4; t++) {
        float z = Z[(size_t)t * BCN + idx];
        float x = g * (z - m);
        x = x * rs + bt;
        v += (x - v) * 0.5f;
        float s = (v - 1.0f >= 0.f) ? 1.f : 0.f;
        v *= (1.f - s);
        outs[t] = s;
    }
    #pragma unroll
    for (int t = 0; t < 4; t++) Z[(size_t)t * BCN + idx] = outs[t];
}

// ---------------------------------------------------------------------------
extern "C" void kernel_launch(void* const* d_in, const int* in_sizes, int n_in,
                              void* d_out, int out_size, void* d_ws, size_t ws_size,
                              hipStream_t stream)
{
    const float* q     = (const float*)d_in[0];
    const float* k     = (const float*)d_in[1];
    const float* v     = (const float*)d_in[2];
    const float* W     = (const float*)d_in[3];
    const float* Wb    = (const float*)d_in[4];
    const float* qg    = (const float*)d_in[5];
    const float* qb    = (const float*)d_in[6];
    const float* kg    = (const float*)d_in[7];
    const float* kbt   = (const float*)d_in[8];
    const float* vg    = (const float*)d_in[9];
    const float* vbt   = (const float*)d_in[10];
    const float* pw    = (const float*)d_in[11];
    const float* pg    = (const float*)d_in[13];
    const float* pbeta = (const float*)d_in[14];

    // workspace carve (~12.3 MB; Y3 lives in d_out)
    char* p = (char*)d_ws;
    unsigned char* spk = (unsigned char*)p; p += (size_t)BCN;                           // 4.19MB
    u64* qmv = (u64*)p;                     p += (size_t)TDIM * BDIM * HDIM * NDIM * 8; // 2MB
    u64* kbits = (u64*)p;                   p += (size_t)TDIM * BDIM * C * 16 * 8;      // 2MB
    u64* vbits = (u64*)p;                   p += (size_t)TDIM * BDIM * C * 16 * 8;      // 2MB
    u16* ktv = (u16*)p;                     p += (size_t)TDIM * BDIM * HDIM * 64 * 64 * 2; // 2.1MB
    float* mean3 = (float*)p;               p += 8192;   // 1536 used
    float* rstd3 = (float*)p;               p += 8192;

    // d_out scratch: Y3 = [br][b][C][N] fp32 (50.3MB of 67.1MB), dead before
    // gemm_proj overwrites d_out with Z.
    float* Y3 = (float*)d_out;
    float* outF = (float*)d_out;
    u16* Ps = (u16*)qmv;         // qmv dead after att_lif_k; split_pw after it
    unsigned char* spkT = spk;   // Q spike bytes dead after qpack

    const float* Gs[3] = {qg, kg, vg};
    const float* Bt[3] = {qb, kbt, vbt};

    gemm_in3_k<<<dim3(8, 4, 24), 256, 0, stream>>>(W, Wb, q, k, v, Y3);
    chan_sum3_k<<<3 * C, 256, 0, stream>>>(Y3, mean3, BDIM);
    chan_var3_k<<<3 * C, 256, 0, stream>>>(Y3, mean3, rstd3, BDIM);
    for (int br = 0; br < 3; ++br) {
        if (br == 0) {
            bn_lif_pack_k<<<BCN / 256, 256, 0, stream>>>(Y3,
                mean3, rstd3, Gs[0], Bt[0], spk);
            qpack_k<<<dim3(64, 16), 256, 0, stream>>>(spk, qmv);
        } else {
            bn_lif_kv_k<<<BCN / 256, 256, 0, stream>>>(Y3 + (size_t)br * BCN,
                mean3 + br * C, rstd3 + br * C, Gs[br], Bt[br],
                br == 1 ? kbits : vbits);
        }
    }
    ktv_k<<<256, 256, 0, stream>>>(kbits, vbits, ktv);
    att_lif_k<<<dim3(64, 16), 256, 0, stream>>>(ktv, qmv, spkT);
    split_pw_k<<<1024, 256, 0, stream>>>(pw, Ps);
    gemm_proj_mfma<<<dim3(8, 4, 32), 256, 0, stream>>>(Ps, spkT, outF);
    chan_sum3_k<<<C, 256, 0, stream>>>(outF, mean3, TDIM * BDIM);
    chan_var3_k<<<C, 256, 0, stream>>>(outF, mean3, rstd3, TDIM * BDIM);
    final_bn_lif_k<<<BCN / 256, 256, 0, stream>>>(outF, mean3, rstd3, pg, pbeta);
}